// Round 1
// baseline (247.150 us; speedup 1.0000x reference)
//
#include <hip/hip_runtime.h>
#include <hip/hip_bf16.h>

// QuaternionLSTMCell on MI355X (gfx950)
// B=2048, I=512, H=512.
// Strategy: fuse the 8 quaternion linears into ONE bf16 GEMM:
//   A [2048 x 4096]  (component-major [x|h] concat, bf16)
//   Wp [3584 x 4096] (Hamilton-expanded weights, B^T layout [N][K], bf16)
//   pre [2048 x 3584] f32 = A @ Wp^T
// N columns: [i_r | f_r | o_r | c_r | c_i | c_j | c_k] * 512 each
// (i/f/o gates only need the real component; c_tilde needs all 4).
// Then an elementwise LSTM-cell epilogue.

#define BDIM 256

typedef __attribute__((ext_vector_type(8))) short short8;
typedef __attribute__((ext_vector_type(4))) float f32x4;

typedef const __attribute__((address_space(1))) void* gptr_t;
typedef __attribute__((address_space(3))) void* lptr_t;

__device__ __forceinline__ ushort f2b(float f) {
  __hip_bfloat16 h = __float2bfloat16(f);
  union { __hip_bfloat16 b; ushort u; } cv;
  cv.b = h;
  return cv.u;
}

// ---------------------------------------------------------------------------
// pack_A: x[B,512,4], h[B,512,4] f32 -> A[B][4096] bf16, component-major:
//   A[b][cin*1024 + pos], pos<512 -> x[b][pos][cin], else h[b][pos-512][cin]
// One thread handles 4 consecutive pos (reads 4 quaternions = 64B contiguous).
// ---------------------------------------------------------------------------
__global__ __launch_bounds__(BDIM) void pack_a_kernel(
    const float* __restrict__ x, const float* __restrict__ h,
    ushort* __restrict__ A) {
  int tid = blockIdx.x * BDIM + threadIdx.x;   // 2048*256 threads
  int b = tid >> 8;
  int pos0 = (tid & 255) << 2;                 // 0..1020, step 4
  const float* src = (pos0 < 512)
      ? (x + ((size_t)b * 512 + pos0) * 4)
      : (h + ((size_t)b * 512 + (pos0 - 512)) * 4);
  float4 q0 = reinterpret_cast<const float4*>(src)[0];
  float4 q1 = reinterpret_cast<const float4*>(src)[1];
  float4 q2 = reinterpret_cast<const float4*>(src)[2];
  float4 q3 = reinterpret_cast<const float4*>(src)[3];
  ushort* Ab = A + (size_t)b * 4096 + pos0;
  union { ushort u[4]; uint2 v; } r0, r1, r2, r3;
  r0.u[0] = f2b(q0.x); r0.u[1] = f2b(q1.x); r0.u[2] = f2b(q2.x); r0.u[3] = f2b(q3.x);
  r1.u[0] = f2b(q0.y); r1.u[1] = f2b(q1.y); r1.u[2] = f2b(q2.y); r1.u[3] = f2b(q3.y);
  r2.u[0] = f2b(q0.z); r2.u[1] = f2b(q1.z); r2.u[2] = f2b(q2.z); r2.u[3] = f2b(q3.z);
  r3.u[0] = f2b(q0.w); r3.u[1] = f2b(q1.w); r3.u[2] = f2b(q2.w); r3.u[3] = f2b(q3.w);
  *reinterpret_cast<uint2*>(Ab)        = r0.v;
  *reinterpret_cast<uint2*>(Ab + 1024) = r1.v;
  *reinterpret_cast<uint2*>(Ab + 2048) = r2.v;
  *reinterpret_cast<uint2*>(Ab + 3072) = r3.v;
}

// ---------------------------------------------------------------------------
// pack_W: Hamilton-expand the 8 weight tensors into Wp[N=3584][K=4096] bf16.
//   n = blk*512 + o; blk 0,1,2 -> gates i,f,o (output comp 0 only);
//                    blk 3..6 -> gate c, output comp co=blk-3.
//   k = cin*1024 + pos; pos<512 -> x-path W weights, else h-path U weights.
//   entry = sign(cin,co) * Wsrc[comp=cin^co][o][i]
// Hamilton sign mask (negative entries), bit index cin*4+co: 0x5390.
// One thread writes 8 consecutive k (one 16B store).
// ---------------------------------------------------------------------------
__global__ __launch_bounds__(BDIM) void pack_w_kernel(
    const float* __restrict__ w0, const float* __restrict__ w1,
    const float* __restrict__ w2, const float* __restrict__ w3,
    const float* __restrict__ u0, const float* __restrict__ u1,
    const float* __restrict__ u2, const float* __restrict__ u3,
    ushort* __restrict__ Wp) {
  int tid = blockIdx.x * BDIM + threadIdx.x;   // 3584*512 threads
  int n = tid >> 9;
  int k = (tid & 511) << 3;
  int blk = n >> 9, o = n & 511;
  int cin = k >> 10, pos = k & 1023;
  int part = pos >> 9, ii = pos & 511;
  int g  = blk < 3 ? blk : 3;
  int co = blk < 3 ? 0 : blk - 3;
  int comp = cin ^ co;
  float sg = ((0x5390u >> ((cin << 2) | co)) & 1u) ? -1.0f : 1.0f;
  const float* base;
  if (part == 0) base = (g == 0) ? w0 : (g == 1) ? w1 : (g == 2) ? w2 : w3;
  else           base = (g == 0) ? u0 : (g == 1) ? u1 : (g == 2) ? u2 : u3;
  const float* p = base + (size_t)comp * 262144 + (size_t)o * 512 + ii;
  float4 v0 = *reinterpret_cast<const float4*>(p);
  float4 v1 = *reinterpret_cast<const float4*>(p + 4);
  union { ushort u[8]; uint4 v; } r;
  r.u[0] = f2b(sg * v0.x); r.u[1] = f2b(sg * v0.y);
  r.u[2] = f2b(sg * v0.z); r.u[3] = f2b(sg * v0.w);
  r.u[4] = f2b(sg * v1.x); r.u[5] = f2b(sg * v1.y);
  r.u[6] = f2b(sg * v1.z); r.u[7] = f2b(sg * v1.w);
  *reinterpret_cast<uint4*>(Wp + (size_t)n * 4096 + k) = r.v;
}

// ---------------------------------------------------------------------------
// GEMM: pre[2048][3584] f32 = A[2048][4096] @ Wp[3584][4096]^T  (bf16 MFMA)
// m97 structure: 128x128 tile, BK=32, 256 threads (4 waves, 2x2 wave grid),
// each wave 64x64 = 4x4 fragments of 16x16x32, global_load_lds width 16.
// ---------------------------------------------------------------------------
__global__ __launch_bounds__(BDIM, 2) void gemm_kernel(
    const ushort* __restrict__ A, const ushort* __restrict__ Bt,
    float* __restrict__ C) {
  __shared__ ushort As[128 * 32];   // 8 KB
  __shared__ ushort Bs[128 * 32];   // 8 KB
  const int t = threadIdx.x;
  const int lane = t & 63;
  const int wid = t >> 6;
  const int wm = wid >> 1, wn = wid & 1;
  const int lrow = lane & 15;
  const int lk = (lane >> 4) << 3;          // 0,8,16,24
  const int m0 = blockIdx.y * 128;
  const int n0 = blockIdx.x * 128;

  f32x4 acc[4][4];
#pragma unroll
  for (int mi = 0; mi < 4; ++mi)
#pragma unroll
    for (int ni = 0; ni < 4; ++ni)
      acc[mi][ni] = (f32x4){0.f, 0.f, 0.f, 0.f};

  const int rA = t >> 2;                    // row within 64-row chunk
  const int cA = (t & 3) << 3;              // k-offset within tile
  const ushort* Abase = A + (size_t)m0 * 4096;
  const ushort* Bbase = Bt + (size_t)n0 * 4096;

  for (int kt = 0; kt < 4096; kt += 32) {
#pragma unroll
    for (int ch = 0; ch < 2; ++ch) {
      const ushort* ga = Abase + (size_t)(ch * 64 + rA) * 4096 + kt + cA;
      const ushort* gb = Bbase + (size_t)(ch * 64 + rA) * 4096 + kt + cA;
      __builtin_amdgcn_global_load_lds((gptr_t)ga, (lptr_t)(As + ch * 2048 + t * 8),
                                       16, 0, 0);
      __builtin_amdgcn_global_load_lds((gptr_t)gb, (lptr_t)(Bs + ch * 2048 + t * 8),
                                       16, 0, 0);
    }
    __syncthreads();
    short8 a[4], b[4];
#pragma unroll
    for (int f = 0; f < 4; ++f) {
      a[f] = *reinterpret_cast<const short8*>(As + (wm * 64 + f * 16 + lrow) * 32 + lk);
      b[f] = *reinterpret_cast<const short8*>(Bs + (wn * 64 + f * 16 + lrow) * 32 + lk);
    }
#pragma unroll
    for (int mi = 0; mi < 4; ++mi)
#pragma unroll
      for (int ni = 0; ni < 4; ++ni)
        acc[mi][ni] = __builtin_amdgcn_mfma_f32_16x16x32_bf16(
            a[mi], b[ni], acc[mi][ni], 0, 0, 0);
    __syncthreads();
  }

  const int orow = (lane >> 4) << 2;
#pragma unroll
  for (int mi = 0; mi < 4; ++mi) {
#pragma unroll
    for (int ni = 0; ni < 4; ++ni) {
      float* cp = C + (size_t)(m0 + wm * 64 + mi * 16 + orow) * 3584
                  + (n0 + wn * 64 + ni * 16 + (lane & 15));
#pragma unroll
      for (int r = 0; r < 4; ++r)
        cp[(size_t)r * 3584] = acc[mi][ni][r];
    }
  }
}

// ---------------------------------------------------------------------------
// cell: LSTM elementwise epilogue.
// pre row layout: [i_r | f_r | o_r | c_r | c_i | c_j | c_k] * 512.
// Biases (h-path only): i/f/o need comp 0; c needs all 4.
// out = [h_t (B*H*4) | c_t (B*H*4)] f32.
// ---------------------------------------------------------------------------
__global__ __launch_bounds__(BDIM) void cell_kernel(
    const float* __restrict__ pre, const float* __restrict__ cin,
    const float* __restrict__ bi, const float* __restrict__ bfg,
    const float* __restrict__ bo, const float* __restrict__ bc,
    float* __restrict__ out) {
  int tid = blockIdx.x * BDIM + threadIdx.x;   // 2048*512 threads
  int o = tid & 511;
  const float* row = pre + (size_t)(tid >> 9) * 3584;
  float4 bcv = *reinterpret_cast<const float4*>(bc + (size_t)o * 4);
  float ip = row[o]        + bi[o << 2];
  float fp = row[512 + o]  + bfg[o << 2];
  float op = row[1024 + o] + bo[o << 2];
  float g0 = tanhf(row[1536 + o] + bcv.x);
  float g1 = tanhf(row[2048 + o] + bcv.y);
  float g2 = tanhf(row[2560 + o] + bcv.z);
  float g3 = tanhf(row[3072 + o] + bcv.w);
  float ig = 1.f / (1.f + expf(-ip));
  float fg = 1.f / (1.f + expf(-fp));
  float og = 1.f / (1.f + expf(-op));
  float4 cv = *reinterpret_cast<const float4*>(cin + (size_t)tid * 4);
  float4 ct, ht;
  ct.x = fg * cv.x + ig * g0;  ht.x = og * tanhf(ct.x);
  ct.y = fg * cv.y + ig * g1;  ht.y = og * tanhf(ct.y);
  ct.z = fg * cv.z + ig * g2;  ht.z = og * tanhf(ct.z);
  ct.w = fg * cv.w + ig * g3;  ht.w = og * tanhf(ct.w);
  *reinterpret_cast<float4*>(out + (size_t)tid * 4) = ht;
  *reinterpret_cast<float4*>(out + 4194304 + (size_t)tid * 4) = ct;
}

// ---------------------------------------------------------------------------
extern "C" void kernel_launch(void* const* d_in, const int* in_sizes, int n_in,
                              void* d_out, int out_size, void* d_ws, size_t ws_size,
                              hipStream_t stream) {
  const float* x   = (const float*)d_in[0];
  const float* h   = (const float*)d_in[1];
  const float* c   = (const float*)d_in[2];
  const float* wi  = (const float*)d_in[3];
  const float* wf  = (const float*)d_in[4];
  const float* wo  = (const float*)d_in[5];
  const float* wc  = (const float*)d_in[6];
  const float* ui  = (const float*)d_in[7];
  const float* uf  = (const float*)d_in[8];
  const float* uo  = (const float*)d_in[9];
  const float* uc  = (const float*)d_in[10];
  const float* bi  = (const float*)d_in[11];
  const float* bf_ = (const float*)d_in[12];
  const float* bo  = (const float*)d_in[13];
  const float* bc  = (const float*)d_in[14];
  float* out = (float*)d_out;

  // Workspace layout (72 MB total):
  //   A   bf16 [2048][4096]  @ 0        (16 MB)
  //   Wp  bf16 [3584][4096]  @ 16 MB    (28 MB)
  //   pre f32  [2048][3584]  @ 44 MB    (28 MB)
  ushort* A  = (ushort*)d_ws;
  ushort* Wp = (ushort*)((char*)d_ws + (size_t)16777216);
  float* pre = (float*)((char*)d_ws + (size_t)16777216 + 29360128);

  hipLaunchKernelGGL(pack_a_kernel, dim3(2048), dim3(BDIM), 0, stream, x, h, A);
  hipLaunchKernelGGL(pack_w_kernel, dim3(7168), dim3(BDIM), 0, stream,
                     wi, wf, wo, wc, ui, uf, uo, uc, Wp);
  hipLaunchKernelGGL(gemm_kernel, dim3(28, 16), dim3(BDIM), 0, stream, A, Wp, pre);
  hipLaunchKernelGGL(cell_kernel, dim3(4096), dim3(BDIM), 0, stream,
                     pre, c, bi, bf_, bo, bc, out);
}

// Round 2
// 240.546 us; speedup vs baseline: 1.0275x; 1.0275x over previous
//
#include <hip/hip_runtime.h>
#include <hip/hip_bf16.h>

// QuaternionLSTMCell on MI355X (gfx950). B=2048, I=512, H=512.
//
// Round 2: 2 kernels.
//  1) pack_kernel: builds A [2048 x 4096] bf16 (component-major [x|h]) and
//     Wp [4096 x 4096] bf16 (Hamilton-expanded, gate-interleaved rows
//     n = o*8 + g; g=0,1,2 -> i/f/o real row, g=3..6 -> c-gate comps,
//     g=7 -> zero dummy pad so each 128-col GEMM tile holds whole gate sets).
//  2) gemm_cell_kernel: pre = A @ Wp^T via bf16 MFMA (128x128 tile, BK=32,
//     grid 32x16 = 512 blocks = exactly 2 blocks/CU, no tail), then the LSTM
//     cell epilogue runs in-block from LDS, writing h_t/c_t directly.
//     No pre buffer, no separate cell kernel.

#define BDIM 256

typedef __attribute__((ext_vector_type(8))) short short8;
typedef __attribute__((ext_vector_type(4))) float f32x4;

typedef const __attribute__((address_space(1))) void* gptr_t;
typedef __attribute__((address_space(3))) void* lptr_t;

__device__ __forceinline__ ushort f2b(float f) {
  __hip_bfloat16 h = __float2bfloat16(f);
  union { __hip_bfloat16 b; ushort u; } cv;
  cv.b = h;
  return cv.u;
}

// ---------------------------------------------------------------------------
// pack_kernel: blocks [0,2048) build A; blocks [2048,10240) build Wp.
//
// A[b][cin*1024 + pos]: pos<512 -> x[b][pos][cin], else h[b][pos-512][cin].
// One A-thread handles 4 consecutive pos (64B contiguous read).
//
// Wp row n = o*8 + g, col k = cin*1024 + pos (pos<512 -> W-path, else U-path).
//   entry = sign(cin,co) * src[comp = cin^co][o][ii],  co = (g<3 ? 0 : g-3)
//   sign mask (negative entries) bit (cin*4+co): 0x5390.  g==7 -> zeros.
// One W-thread writes 8 consecutive k (16B store). g is wave-uniform
// (one n spans 8 waves), so no divergence.
// ---------------------------------------------------------------------------
__global__ __launch_bounds__(BDIM) void pack_kernel(
    const float* __restrict__ x, const float* __restrict__ h,
    const float* __restrict__ w0, const float* __restrict__ w1,
    const float* __restrict__ w2, const float* __restrict__ w3,
    const float* __restrict__ u0, const float* __restrict__ u1,
    const float* __restrict__ u2, const float* __restrict__ u3,
    ushort* __restrict__ A, ushort* __restrict__ Wp) {
  if (blockIdx.x < 2048) {
    int tid = blockIdx.x * BDIM + threadIdx.x;     // 2048*256 threads
    int b = tid >> 8;
    int pos0 = (tid & 255) << 2;                   // 0..1020 step 4
    const float* src = (pos0 < 512)
        ? (x + ((size_t)b * 512 + pos0) * 4)
        : (h + ((size_t)b * 512 + (pos0 - 512)) * 4);
    float4 q0 = reinterpret_cast<const float4*>(src)[0];
    float4 q1 = reinterpret_cast<const float4*>(src)[1];
    float4 q2 = reinterpret_cast<const float4*>(src)[2];
    float4 q3 = reinterpret_cast<const float4*>(src)[3];
    ushort* Ab = A + (size_t)b * 4096 + pos0;
    union { ushort u[4]; uint2 v; } r0, r1, r2, r3;
    r0.u[0] = f2b(q0.x); r0.u[1] = f2b(q1.x); r0.u[2] = f2b(q2.x); r0.u[3] = f2b(q3.x);
    r1.u[0] = f2b(q0.y); r1.u[1] = f2b(q1.y); r1.u[2] = f2b(q2.y); r1.u[3] = f2b(q3.y);
    r2.u[0] = f2b(q0.z); r2.u[1] = f2b(q1.z); r2.u[2] = f2b(q2.z); r2.u[3] = f2b(q3.z);
    r3.u[0] = f2b(q0.w); r3.u[1] = f2b(q1.w); r3.u[2] = f2b(q2.w); r3.u[3] = f2b(q3.w);
    *reinterpret_cast<uint2*>(Ab)        = r0.v;
    *reinterpret_cast<uint2*>(Ab + 1024) = r1.v;
    *reinterpret_cast<uint2*>(Ab + 2048) = r2.v;
    *reinterpret_cast<uint2*>(Ab + 3072) = r3.v;
  } else {
    int tid = (blockIdx.x - 2048) * BDIM + threadIdx.x;  // 4096*512 threads
    int n = tid >> 9;                    // 0..4095
    int k = (tid & 511) << 3;            // 0..4088
    ushort* dst = Wp + (size_t)n * 4096 + k;
    int o = n >> 3, g = n & 7;
    if (g == 7) {
      uint4 z = {0u, 0u, 0u, 0u};
      *reinterpret_cast<uint4*>(dst) = z;
      return;
    }
    int cin = k >> 10, pos = k & 1023;
    int part = pos >> 9, ii = pos & 511;
    int gi = (g < 3) ? g : 3;
    int co = (g < 3) ? 0 : g - 3;
    int comp = cin ^ co;
    float sg = ((0x5390u >> ((cin << 2) | co)) & 1u) ? -1.0f : 1.0f;
    const float* base;
    if (part == 0) base = (gi == 0) ? w0 : (gi == 1) ? w1 : (gi == 2) ? w2 : w3;
    else           base = (gi == 0) ? u0 : (gi == 1) ? u1 : (gi == 2) ? u2 : u3;
    const float* p = base + (size_t)comp * 262144 + (size_t)o * 512 + ii;
    float4 v0 = *reinterpret_cast<const float4*>(p);
    float4 v1 = *reinterpret_cast<const float4*>(p + 4);
    union { ushort u[8]; uint4 v; } r;
    r.u[0] = f2b(sg * v0.x); r.u[1] = f2b(sg * v0.y);
    r.u[2] = f2b(sg * v0.z); r.u[3] = f2b(sg * v0.w);
    r.u[4] = f2b(sg * v1.x); r.u[5] = f2b(sg * v1.y);
    r.u[6] = f2b(sg * v1.z); r.u[7] = f2b(sg * v1.w);
    *reinterpret_cast<uint4*>(dst) = r.v;
  }
}

// ---------------------------------------------------------------------------
// gemm_cell: pre[2048][4096] = A[2048][4096] @ Wp[4096][4096]^T (bf16 MFMA),
// epilogue consumes the 128x128 f32 tile in-block (all 8 gate slots of each
// (b,o) pair are inside the tile) and writes h_t / c_t.
// 4 waves (2x2), wave = 64x64 = 4x4 frags of 16x16x32. BK=32.
// ---------------------------------------------------------------------------
__global__ __launch_bounds__(BDIM, 2) void gemm_cell_kernel(
    const ushort* __restrict__ A, const ushort* __restrict__ Wp,
    const float* __restrict__ cin_, const float* __restrict__ bi,
    const float* __restrict__ bfg, const float* __restrict__ bo,
    const float* __restrict__ bc, float* __restrict__ out) {
  __shared__ ushort As[128 * 32];    // 8 KB
  __shared__ ushort Bs[128 * 32];    // 8 KB
  __shared__ float  Es[64 * 132];    // 33 KB epilogue tile (stride 132 = pad)

  const int t = threadIdx.x;
  const int lane = t & 63;
  const int wid = t >> 6;
  const int wm = wid >> 1, wn = wid & 1;
  const int lrow = lane & 15;
  const int lk = (lane >> 4) << 3;           // 0,8,16,24
  const int m0 = blockIdx.y * 128;
  const int n0 = blockIdx.x * 128;

  f32x4 acc[4][4];
#pragma unroll
  for (int mi = 0; mi < 4; ++mi)
#pragma unroll
    for (int ni = 0; ni < 4; ++ni)
      acc[mi][ni] = (f32x4){0.f, 0.f, 0.f, 0.f};

  const int rA = t >> 2;                     // row in 64-row chunk
  const int cA = (t & 3) << 3;               // k offset (elements)
  const ushort* Abase = A + (size_t)m0 * 4096;
  const ushort* Bbase = Wp + (size_t)n0 * 4096;

  for (int kt = 0; kt < 4096; kt += 32) {
#pragma unroll
    for (int ch = 0; ch < 2; ++ch) {
      const ushort* ga = Abase + (size_t)(ch * 64 + rA) * 4096 + kt + cA;
      const ushort* gb = Bbase + (size_t)(ch * 64 + rA) * 4096 + kt + cA;
      __builtin_amdgcn_global_load_lds((gptr_t)ga, (lptr_t)(As + ch * 2048 + t * 8),
                                       16, 0, 0);
      __builtin_amdgcn_global_load_lds((gptr_t)gb, (lptr_t)(Bs + ch * 2048 + t * 8),
                                       16, 0, 0);
    }
    __syncthreads();
    short8 a[4], b[4];
#pragma unroll
    for (int f = 0; f < 4; ++f) {
      a[f] = *reinterpret_cast<const short8*>(As + (wm * 64 + f * 16 + lrow) * 32 + lk);
      b[f] = *reinterpret_cast<const short8*>(Bs + (wn * 64 + f * 16 + lrow) * 32 + lk);
    }
#pragma unroll
    for (int mi = 0; mi < 4; ++mi)
#pragma unroll
      for (int ni = 0; ni < 4; ++ni)
        acc[mi][ni] = __builtin_amdgcn_mfma_f32_16x16x32_bf16(
            a[mi], b[ni], acc[mi][ni], 0, 0, 0);
    __syncthreads();
  }

  // ---- fused LSTM cell epilogue ----
  // Block tile covers b in [m0, m0+128), o in [o0, o0+16), 8 gate slots/o.
  const int o0 = blockIdx.x * 16;
  const int lr4 = (lane >> 4) << 2;          // 0,4,8,12

#pragma unroll
  for (int ch = 0; ch < 2; ++ch) {
    if (wm == ch) {
      // dump this wave's acc rows (local rows 0..63 of the chunk) to Es
#pragma unroll
      for (int mi = 0; mi < 4; ++mi)
#pragma unroll
        for (int ni = 0; ni < 4; ++ni) {
          float* dst = Es + (mi * 16 + lr4) * 132 + wn * 64 + ni * 16 + lrow;
#pragma unroll
          for (int r = 0; r < 4; ++r) dst[r * 132] = acc[mi][ni][r];
        }
    }
    __syncthreads();
    // 64 rows x 16 o = 1024 pairs, 4 per thread
#pragma unroll
    for (int i = 0; i < 4; ++i) {
      int p = t + i * 256;
      int bl = p >> 4;
      int ol = p & 15;
      const float* e = Es + bl * 132 + ol * 8;
      int b = m0 + ch * 64 + bl;
      int o = o0 + ol;
      float4 bcv = *reinterpret_cast<const float4*>(bc + (size_t)o * 4);
      float ip = e[0] + bi[o << 2];
      float fp = e[1] + bfg[o << 2];
      float op = e[2] + bo[o << 2];
      float g0 = tanhf(e[3] + bcv.x);
      float g1 = tanhf(e[4] + bcv.y);
      float g2 = tanhf(e[5] + bcv.z);
      float g3 = tanhf(e[6] + bcv.w);
      float ig = 1.f / (1.f + expf(-ip));
      float fg = 1.f / (1.f + expf(-fp));
      float og = 1.f / (1.f + expf(-op));
      float4 cv = *reinterpret_cast<const float4*>(cin_ + ((size_t)b * 512 + o) * 4);
      float4 ct, ht;
      ct.x = fg * cv.x + ig * g0;  ht.x = og * tanhf(ct.x);
      ct.y = fg * cv.y + ig * g1;  ht.y = og * tanhf(ct.y);
      ct.z = fg * cv.z + ig * g2;  ht.z = og * tanhf(ct.z);
      ct.w = fg * cv.w + ig * g3;  ht.w = og * tanhf(ct.w);
      *reinterpret_cast<float4*>(out + ((size_t)b * 512 + o) * 4) = ht;
      *reinterpret_cast<float4*>(out + 4194304 + ((size_t)b * 512 + o) * 4) = ct;
    }
    __syncthreads();
  }
}

// ---------------------------------------------------------------------------
extern "C" void kernel_launch(void* const* d_in, const int* in_sizes, int n_in,
                              void* d_out, int out_size, void* d_ws, size_t ws_size,
                              hipStream_t stream) {
  const float* x   = (const float*)d_in[0];
  const float* h   = (const float*)d_in[1];
  const float* c   = (const float*)d_in[2];
  const float* wi  = (const float*)d_in[3];
  const float* wf  = (const float*)d_in[4];
  const float* wo  = (const float*)d_in[5];
  const float* wc  = (const float*)d_in[6];
  const float* ui  = (const float*)d_in[7];
  const float* uf  = (const float*)d_in[8];
  const float* uo  = (const float*)d_in[9];
  const float* uc  = (const float*)d_in[10];
  const float* bi  = (const float*)d_in[11];
  const float* bf_ = (const float*)d_in[12];
  const float* bo  = (const float*)d_in[13];
  const float* bc  = (const float*)d_in[14];
  float* out = (float*)d_out;

  // Workspace: A bf16 [2048][4096] @ 0 (16 MB); Wp bf16 [4096][4096] @ 16 MB (32 MB)
  ushort* A  = (ushort*)d_ws;
  ushort* Wp = (ushort*)((char*)d_ws + (size_t)16777216);

  hipLaunchKernelGGL(pack_kernel, dim3(10240), dim3(BDIM), 0, stream,
                     x, h, wi, wf, wo, wc, ui, uf, uo, uc, A, Wp);
  hipLaunchKernelGGL(gemm_cell_kernel, dim3(32, 16), dim3(BDIM), 0, stream,
                     A, Wp, c, bi, bf_, bo, bc, out);
}

// Round 4
// 214.323 us; speedup vs baseline: 1.1532x; 1.1224x over previous
//
#include <hip/hip_runtime.h>
#include <hip/hip_bf16.h>

// QuaternionLSTMCell on MI355X (gfx950). B=2048, I=512, H=512.
//
// Round 4 = Round 3 resubmitted (round-3 bench died to an infra flake:
// same "container failed twice" error as the round-0 stub, which cannot
// hang -> acquisition failure, not kernel timeout. Kernel re-audited for
// barrier balance / pipeline races / global_load_lds dest-linearity.)
//
//  pack_kernel: A [2048x4096] bf16, Wp [4096x4096] bf16 (Hamilton-expanded,
//    gate-interleaved n=o*8+g, g=7 zero pad). Both stored with a 16B-chunk
//    XOR swizzle within each 64-elem K-window: col ^= (row&7)<<3, so that
//    linear global_load_lds staging yields a bank-conflict-free LDS image
//    (read side applies the same XOR).
//  gemm_cell_kernel: BM=128, BN=256, BK=64, 512 threads (8 waves 2x4),
//    grid 256 = 1 block/CU, XCD-rectangle swizzle (8bx x 4by per XCD for L2
//    locality). 3-slot LDS pipeline with counted s_waitcnt vmcnt(6) + raw
//    s_barrier (never drains to 0 in steady state; race-free: prefetch slot
//    (kt+2)%3 is never concurrently read). Fused LSTM-cell epilogue.

#define BDIM 256
#define GDIM 512

typedef __attribute__((ext_vector_type(8))) short short8;
typedef __attribute__((ext_vector_type(4))) float f32x4;

typedef const __attribute__((address_space(1))) void* gptr_t;
typedef __attribute__((address_space(3))) void* lptr_t;

__device__ __forceinline__ ushort f2b(float f) {
  __hip_bfloat16 h = __float2bfloat16(f);
  union { __hip_bfloat16 b; ushort u; } cv;
  cv.b = h;
  return cv.u;
}

// ---------------------------------------------------------------------------
// pack_kernel: blocks [0,2048) build A; blocks [2048,10240) build Wp.
// Swizzle: destination column = col ^ ((row&7)<<3)  (16B chunks permuted
// within each 64-element K-window; window- and 8-elem-group-preserving).
// ---------------------------------------------------------------------------
__global__ __launch_bounds__(BDIM) void pack_kernel(
    const float* __restrict__ x, const float* __restrict__ h,
    const float* __restrict__ w0, const float* __restrict__ w1,
    const float* __restrict__ w2, const float* __restrict__ w3,
    const float* __restrict__ u0, const float* __restrict__ u1,
    const float* __restrict__ u2, const float* __restrict__ u3,
    ushort* __restrict__ A, ushort* __restrict__ Wp) {
  if (blockIdx.x < 2048) {
    int tid = blockIdx.x * BDIM + threadIdx.x;
    int b = tid >> 8;
    int pos0 = (tid & 255) << 2;                   // 0..1020 step 4
    const float* src = (pos0 < 512)
        ? (x + ((size_t)b * 512 + pos0) * 4)
        : (h + ((size_t)b * 512 + (pos0 - 512)) * 4);
    float4 q0 = reinterpret_cast<const float4*>(src)[0];
    float4 q1 = reinterpret_cast<const float4*>(src)[1];
    float4 q2 = reinterpret_cast<const float4*>(src)[2];
    float4 q3 = reinterpret_cast<const float4*>(src)[3];
    int swz = (b & 7) << 3;
    ushort* Ab = A + (size_t)b * 4096 + (pos0 ^ swz);
    union { ushort u[4]; uint2 v; } r0, r1, r2, r3;
    r0.u[0] = f2b(q0.x); r0.u[1] = f2b(q1.x); r0.u[2] = f2b(q2.x); r0.u[3] = f2b(q3.x);
    r1.u[0] = f2b(q0.y); r1.u[1] = f2b(q1.y); r1.u[2] = f2b(q2.y); r1.u[3] = f2b(q3.y);
    r2.u[0] = f2b(q0.z); r2.u[1] = f2b(q1.z); r2.u[2] = f2b(q2.z); r2.u[3] = f2b(q3.z);
    r3.u[0] = f2b(q0.w); r3.u[1] = f2b(q1.w); r3.u[2] = f2b(q2.w); r3.u[3] = f2b(q3.w);
    *reinterpret_cast<uint2*>(Ab)        = r0.v;
    *reinterpret_cast<uint2*>(Ab + 1024) = r1.v;
    *reinterpret_cast<uint2*>(Ab + 2048) = r2.v;
    *reinterpret_cast<uint2*>(Ab + 3072) = r3.v;
  } else {
    int tid = (blockIdx.x - 2048) * BDIM + threadIdx.x;
    int n = tid >> 9;                    // 0..4095
    int k = (tid & 511) << 3;            // 0..4088
    int swz = (n & 7) << 3;
    ushort* dst = Wp + (size_t)n * 4096 + (k ^ swz);
    int o = n >> 3, g = n & 7;
    if (g == 7) {
      uint4 z = {0u, 0u, 0u, 0u};
      *reinterpret_cast<uint4*>(dst) = z;
      return;
    }
    int cin = k >> 10, pos = k & 1023;
    int part = pos >> 9, ii = pos & 511;
    int gi = (g < 3) ? g : 3;
    int co = (g < 3) ? 0 : g - 3;
    int comp = cin ^ co;
    float sg = ((0x5390u >> ((cin << 2) | co)) & 1u) ? -1.0f : 1.0f;
    const float* base;
    if (part == 0) base = (gi == 0) ? w0 : (gi == 1) ? w1 : (gi == 2) ? w2 : w3;
    else           base = (gi == 0) ? u0 : (gi == 1) ? u1 : (gi == 2) ? u2 : u3;
    const float* p = base + (size_t)comp * 262144 + (size_t)o * 512 + ii;
    float4 v0 = *reinterpret_cast<const float4*>(p);
    float4 v1 = *reinterpret_cast<const float4*>(p + 4);
    union { ushort u[8]; uint4 v; } r;
    r.u[0] = f2b(sg * v0.x); r.u[1] = f2b(sg * v0.y);
    r.u[2] = f2b(sg * v0.z); r.u[3] = f2b(sg * v0.w);
    r.u[4] = f2b(sg * v1.x); r.u[5] = f2b(sg * v1.y);
    r.u[6] = f2b(sg * v1.z); r.u[7] = f2b(sg * v1.w);
    *reinterpret_cast<uint4*>(dst) = r.v;
  }
}

// ---------------------------------------------------------------------------
// gemm_cell: pre = A @ Wp^T, fused LSTM cell.
// ---------------------------------------------------------------------------
__global__ __launch_bounds__(GDIM, 2) void gemm_cell_kernel(
    const ushort* __restrict__ A, const ushort* __restrict__ Wp,
    const float* __restrict__ cin_, const float* __restrict__ bi,
    const float* __restrict__ bfg, const float* __restrict__ bo,
    const float* __restrict__ bc, float* __restrict__ out) {
  // LDS: As 3 slots x [128][64] (16KB), Bs 3 slots x [256][64] (32KB) = 144KB
  __shared__ ushort SMEM[73728];
  ushort* As = SMEM;              // slot s at As + s*8192
  ushort* Bs = SMEM + 24576;      // slot s at Bs + s*16384

  const int t = threadIdx.x;
  const int lane = t & 63;
  const int wid = t >> 6;
  const int wm = wid >> 2;              // 0..1
  const int wn = wid & 3;               // 0..3
  const int lrow = lane & 15;
  const int lk8 = (lane >> 4) << 3;     // 0,8,16,24 (elem col within 32-K)
  const int swzE = (lrow & 7) << 3;

  // XCD-rectangle swizzle: 8bx x 4by per XCD (bijective)
  const int bid = blockIdx.x;           // 0..255
  const int xcd = bid & 7;
  const int loc = bid >> 3;             // 0..31
  const int bx = (xcd & 1) * 8 + (loc & 7);    // 0..15
  const int by = (xcd >> 1) * 4 + (loc >> 3);  // 0..15
  const int m0 = by * 128;
  const int n0 = bx * 256;

  f32x4 acc[4][4];
#pragma unroll
  for (int mi = 0; mi < 4; ++mi)
#pragma unroll
    for (int ni = 0; ni < 4; ++ni)
      acc[mi][ni] = (f32x4){0.f, 0.f, 0.f, 0.f};

  const ushort* Ag = A + (size_t)m0 * 4096;
  const ushort* Bg = Wp + (size_t)n0 * 4096;
  const int c8 = (t & 7) << 3;          // elem col chunk start

  // staging: A = 2 loads/thread (j = t, t+512); B = 4 loads (j = t..t+1536)
#define STAGE_A(KT, S, I)                                                     \
  {                                                                           \
    int j = t + (I) * 512;                                                    \
    __builtin_amdgcn_global_load_lds(                                         \
        (gptr_t)(Ag + (size_t)(j >> 3) * 4096 + (KT) * 64 + c8),              \
        (lptr_t)(As + (S) * 8192 + j * 8), 16, 0, 0);                         \
  }
#define STAGE_B(KT, S, I)                                                     \
  {                                                                           \
    int j = t + (I) * 512;                                                    \
    __builtin_amdgcn_global_load_lds(                                         \
        (gptr_t)(Bg + (size_t)(j >> 3) * 4096 + (KT) * 64 + c8),              \
        (lptr_t)(Bs + (S) * 16384 + j * 8), 16, 0, 0);                        \
  }

  // prologue: stage kt=0 -> slot0, kt=1 -> slot1
  STAGE_A(0, 0, 0) STAGE_A(0, 0, 1)
  STAGE_B(0, 0, 0) STAGE_B(0, 0, 1) STAGE_B(0, 0, 2) STAGE_B(0, 0, 3)
  STAGE_A(1, 1, 0) STAGE_A(1, 1, 1)
  STAGE_B(1, 1, 0) STAGE_B(1, 1, 1) STAGE_B(1, 1, 2) STAGE_B(1, 1, 3)
  asm volatile("s_waitcnt vmcnt(6)" ::: "memory");
  __builtin_amdgcn_s_barrier();
  __builtin_amdgcn_sched_barrier(0);

  int cur = 0;
  for (int kt = 0; kt < 64; ++kt) {
    const int pf = (kt < 62);
    const int ps = (cur >= 1) ? cur - 1 : 2;     // (cur+2)%3
    const ushort* Ac = As + cur * 8192;
    const ushort* Bc = Bs + cur * 16384;

    // ---- phase 0: kk = 0 ----
    {
      const int c0 = lk8 ^ swzE;
      short8 af[4], bf[4];
#pragma unroll
      for (int mi = 0; mi < 4; ++mi)
        af[mi] = *reinterpret_cast<const short8*>(Ac + (wm * 64 + mi * 16 + lrow) * 64 + c0);
#pragma unroll
      for (int ni = 0; ni < 4; ++ni)
        bf[ni] = *reinterpret_cast<const short8*>(Bc + (wn * 64 + ni * 16 + lrow) * 64 + c0);
      if (pf) { STAGE_A(kt + 2, ps, 0) STAGE_A(kt + 2, ps, 1) STAGE_B(kt + 2, ps, 0) }
      __builtin_amdgcn_s_setprio(1);
#pragma unroll
      for (int mi = 0; mi < 4; ++mi)
#pragma unroll
        for (int ni = 0; ni < 4; ++ni)
          acc[mi][ni] = __builtin_amdgcn_mfma_f32_16x16x32_bf16(
              af[mi], bf[ni], acc[mi][ni], 0, 0, 0);
      __builtin_amdgcn_s_setprio(0);
    }
    // ---- phase 1: kk = 1 ----
    {
      const int c1 = (32 + lk8) ^ swzE;
      short8 af[4], bf[4];
#pragma unroll
      for (int mi = 0; mi < 4; ++mi)
        af[mi] = *reinterpret_cast<const short8*>(Ac + (wm * 64 + mi * 16 + lrow) * 64 + c1);
#pragma unroll
      for (int ni = 0; ni < 4; ++ni)
        bf[ni] = *reinterpret_cast<const short8*>(Bc + (wn * 64 + ni * 16 + lrow) * 64 + c1);
      if (pf) { STAGE_B(kt + 2, ps, 1) STAGE_B(kt + 2, ps, 2) STAGE_B(kt + 2, ps, 3) }
      __builtin_amdgcn_s_setprio(1);
#pragma unroll
      for (int mi = 0; mi < 4; ++mi)
#pragma unroll
        for (int ni = 0; ni < 4; ++ni)
          acc[mi][ni] = __builtin_amdgcn_mfma_f32_16x16x32_bf16(
              af[mi], bf[ni], acc[mi][ni], 0, 0, 0);
      __builtin_amdgcn_s_setprio(0);
    }

    if (kt < 62)       { asm volatile("s_waitcnt vmcnt(6)" ::: "memory"); }
    else if (kt == 62) { asm volatile("s_waitcnt vmcnt(0)" ::: "memory"); }
    __builtin_amdgcn_s_barrier();
    __builtin_amdgcn_sched_barrier(0);
    cur = (cur == 2) ? 0 : cur + 1;
  }
  __syncthreads();   // full drain before aliasing LDS for the epilogue

  // ---- fused LSTM cell epilogue ----
  // Block covers b in [m0,m0+128), o in [o0,o0+32), 8 gate slots per o.
  // Es[16][260] f32 aliased onto SMEM; 8 chunks (wmc x mi) of 16 b-rows.
  float* Es = (float*)SMEM;
  const int o0 = bx * 32;
  const int lr4 = (lane >> 4) << 2;     // 0,4,8,12

#pragma unroll
  for (int wmc = 0; wmc < 2; ++wmc) {
#pragma unroll
    for (int mi = 0; mi < 4; ++mi) {
      if (wm == wmc) {
#pragma unroll
        for (int ni = 0; ni < 4; ++ni) {
          float* dst = Es + lr4 * 260 + wn * 64 + ni * 16 + lrow;
#pragma unroll
          for (int r = 0; r < 4; ++r) dst[r * 260] = acc[mi][ni][r];
        }
      }
      __syncthreads();
      {
        int bl = t >> 5;                // 0..15
        int ol = t & 31;                // 0..31
        const float* e = Es + bl * 260 + ol * 8;
        int b = m0 + wmc * 64 + mi * 16 + bl;
        int o = o0 + ol;
        float4 bcv = *reinterpret_cast<const float4*>(bc + (size_t)o * 4);
        float ip = e[0] + bi[o << 2];
        float fp = e[1] + bfg[o << 2];
        float op = e[2] + bo[o << 2];
        float g0 = tanhf(e[3] + bcv.x);
        float g1 = tanhf(e[4] + bcv.y);
        float g2 = tanhf(e[5] + bcv.z);
        float g3 = tanhf(e[6] + bcv.w);
        float ig = 1.f / (1.f + expf(-ip));
        float fg = 1.f / (1.f + expf(-fp));
        float og = 1.f / (1.f + expf(-op));
        float4 cv = *reinterpret_cast<const float4*>(cin_ + ((size_t)b * 512 + o) * 4);
        float4 ct, ht;
        ct.x = fg * cv.x + ig * g0;  ht.x = og * tanhf(ct.x);
        ct.y = fg * cv.y + ig * g1;  ht.y = og * tanhf(ct.y);
        ct.z = fg * cv.z + ig * g2;  ht.z = og * tanhf(ct.z);
        ct.w = fg * cv.w + ig * g3;  ht.w = og * tanhf(ct.w);
        *reinterpret_cast<float4*>(out + ((size_t)b * 512 + o) * 4) = ht;
        *reinterpret_cast<float4*>(out + 4194304 + ((size_t)b * 512 + o) * 4) = ct;
      }
      __syncthreads();
    }
  }
#undef STAGE_A
#undef STAGE_B
}

// ---------------------------------------------------------------------------
extern "C" void kernel_launch(void* const* d_in, const int* in_sizes, int n_in,
                              void* d_out, int out_size, void* d_ws, size_t ws_size,
                              hipStream_t stream) {
  const float* x   = (const float*)d_in[0];
  const float* h   = (const float*)d_in[1];
  const float* c   = (const float*)d_in[2];
  const float* wi  = (const float*)d_in[3];
  const float* wf  = (const float*)d_in[4];
  const float* wo  = (const float*)d_in[5];
  const float* wc  = (const float*)d_in[6];
  const float* ui  = (const float*)d_in[7];
  const float* uf  = (const float*)d_in[8];
  const float* uo  = (const float*)d_in[9];
  const float* uc  = (const float*)d_in[10];
  const float* bi  = (const float*)d_in[11];
  const float* bf_ = (const float*)d_in[12];
  const float* bo  = (const float*)d_in[13];
  const float* bc  = (const float*)d_in[14];
  float* out = (float*)d_out;

  ushort* A  = (ushort*)d_ws;                                  // 16 MB
  ushort* Wp = (ushort*)((char*)d_ws + (size_t)16777216);      // 32 MB

  hipLaunchKernelGGL(pack_kernel, dim3(10240), dim3(BDIM), 0, stream,
                     x, h, wi, wf, wo, wc, ui, uf, uo, uc, A, Wp);
  hipLaunchKernelGGL(gemm_cell_kernel, dim3(256), dim3(GDIM), 0, stream,
                     A, Wp, c, bi, bf_, bo, bc, out);
}